// Round 7
// baseline (92.516 us; speedup 1.0000x reference)
//
#include <hip/hip_runtime.h>
#include <hip/hip_bf16.h>
#include <stdint.h>

// S5 layer on MI355X — round 7:
//   gemm1  : B(Mv)-resident-in-LDS (128KB, staged once, swizzled), A fp32->reg
//            direct in MFMA layout, ZERO main-loop barriers. Writes Vb bf16 + Ub bf16.
//   scan   : exact 3-phase (shuffle-scan carry), V in bf16.
//   gemm23 : 256x256, BK=64, 2 phases/tile by K-half, counted vmcnt(4) (T4),
//            raw s_barrier + sched_barrier fences, T2 swizzle, T5 setprio, T1 XCD.

#define BATCH 8
#define SEQ   4096
#define DMODEL 512
#define HALF  64
#define CHUNK 64
#define NCHUNK (SEQ / CHUNK)   // 64
#define NT    10               // 640 / 64 K-tiles in gemm23

typedef __attribute__((ext_vector_type(8))) short short8;
typedef __attribute__((ext_vector_type(4))) float f32x4;

__device__ __forceinline__ unsigned short f2bf(float f) {
    unsigned int u = __float_as_uint(f);
    u += 0x7fffu + ((u >> 16) & 1u);
    return (unsigned short)(u >> 16);
}
__device__ __forceinline__ float bf2f(unsigned short s) {
    return __uint_as_float((unsigned)s << 16);
}

#define GLOAD_LDS16(g, l)                                                    \
    __builtin_amdgcn_global_load_lds(                                        \
        (const __attribute__((address_space(1))) unsigned int*)(g),          \
        (__attribute__((address_space(3))) unsigned int*)(l), 16, 0, 0)

// ---------------- precompute ----------------

__global__ void k_consts(const float* __restrict__ logLr,
                         const float* __restrict__ Li_in,
                         const float* __restrict__ logDelta,
                         float* __restrict__ sr, float* __restrict__ si,
                         float* __restrict__ ApR, float* __restrict__ ApI) {
    int n = threadIdx.x;  // 0..63
    float Delta = expf(logDelta[0]);
    float llr = fminf(fmaxf(logLr[n], -10.f), 10.f);
    float Lr = -expf(llr);
    float Li = Li_in[n];
    float dr = 1.f - 0.5f * Delta * Lr;
    float di = -0.5f * Delta * Li;
    float dn = dr * dr + di * di;
    float nr = 1.f + 0.5f * Delta * Lr;
    float ni = 0.5f * Delta * Li;
    float Ar = (nr * dr + ni * di) / dn;
    float Ai = (ni * dr - nr * di) / dn;
    sr[n] = Delta * dr / dn;
    si[n] = -Delta * di / dn;
    float pr = 1.f, pi = 0.f;
    for (int k = 0; k <= CHUNK; ++k) {
        ApR[k * HALF + n] = pr;
        ApI[k * HALF + n] = pi;
        float npr = pr * Ar - pi * Ai;
        float npi = pr * Ai + pi * Ar;
        pr = npr; pi = npi;
    }
}

__global__ void k_build_Mv(const float* __restrict__ Br, const float* __restrict__ Bi,
                           const float* __restrict__ sr, const float* __restrict__ si,
                           unsigned short* __restrict__ Mv) {
    int np = blockIdx.x, p = threadIdx.x;
    int n = np & 63;
    float br = Br[n * DMODEL + p], bi = Bi[n * DMODEL + p];
    float v = (np < HALF) ? (sr[n] * br - si[n] * bi)
                          : (si[n] * br + sr[n] * bi);
    Mv[np * DMODEL + p] = f2bf(v);
}

__global__ void k_build_W(const float* __restrict__ Cr, const float* __restrict__ Ci,
                          const float* __restrict__ D, unsigned short* __restrict__ W) {
    int p = blockIdx.x, j = threadIdx.x;
    float v;
    if (j < HALF) v = 2.f * Cr[p * HALF + j];
    else if (j < 2 * HALF) v = -2.f * Ci[p * HALF + (j - HALF)];
    else v = D[p * DMODEL + (j - 2 * HALF)];
    W[p * 640 + j] = f2bf(v);
}

// ---------------- scan (exact; V in bf16) ----------------

__global__ void k_scanA(const unsigned short* __restrict__ Vb,
                        const float* __restrict__ ApR, const float* __restrict__ ApI,
                        float* __restrict__ E) {
    int tid = threadIdx.x;
    int n = tid & 63;
    int c = ((blockIdx.x & 31) << 1) + (tid >> 6);
    int b = blockIdx.x >> 5;
    float Ar = ApR[HALF + n], Ai = ApI[HALF + n];
    float xr = 0.f, xi = 0.f;
    size_t base = ((size_t)b * SEQ + (size_t)c * CHUNK) * 128 + n;
    for (int tl = 0; tl < CHUNK; ++tl) {
        float vr = bf2f(Vb[base]), vi = bf2f(Vb[base + 64]);
        float nxr = Ar * xr - Ai * xi + vr;
        float nxi = Ar * xi + Ai * xr + vi;
        xr = nxr; xi = nxi;
        base += 128;
    }
    int eidx = ((b * NCHUNK + c) * 2) * HALF + n;
    E[eidx] = xr; E[eidx + 64] = xi;
}

__global__ void k_scanB(const float* __restrict__ E, float* __restrict__ Carry,
                        const float* __restrict__ ApR, const float* __restrict__ ApI) {
    int lane = threadIdx.x & 63;   // chunk c
    int wv = threadIdx.x >> 6;     // 0..7
    int b = blockIdx.x;
    for (int n = wv; n < HALF; n += 8) {
        float wr = ApR[CHUNK * HALF + n], wi = ApI[CHUNK * HALF + n];  // A^64
        int idx = ((b * NCHUNK + lane) * 2) * HALF + n;
        float sR = E[idx], sI = E[idx + 64];
#pragma unroll
        for (int s = 1; s < 64; s <<= 1) {
            float pR = __shfl_up(sR, s, 64);
            float pI = __shfl_up(sI, s, 64);
            if (lane >= s) {
                sR += wr * pR - wi * pI;
                sI += wr * pI + wi * pR;
            }
            float nwr = wr * wr - wi * wi;
            float nwi = 2.f * wr * wi;
            wr = nwr; wi = nwi;
        }
        float cR = __shfl_up(sR, 1, 64);
        float cI = __shfl_up(sI, 1, 64);
        if (lane == 0) { cR = 0.f; cI = 0.f; }
        Carry[idx] = cR; Carry[idx + 64] = cI;
    }
}

__global__ void k_scanC(const unsigned short* __restrict__ Vb,
                        const float* __restrict__ Carry,
                        const float* __restrict__ ApR, const float* __restrict__ ApI,
                        unsigned short* __restrict__ Xb) {
    int tid = threadIdx.x;
    int n = tid & 63;
    int c = ((blockIdx.x & 31) << 1) + (tid >> 6);
    int b = blockIdx.x >> 5;
    int cidx = ((b * NCHUNK + c) * 2) * HALF + n;
    float xr = Carry[cidx], xi = Carry[cidx + 64];
    float Ar = ApR[HALF + n], Ai = ApI[HALF + n];
    size_t base = ((size_t)b * SEQ + (size_t)c * CHUNK) * 128 + n;
    for (int tl = 0; tl < CHUNK; ++tl) {
        float vr = bf2f(Vb[base]), vi = bf2f(Vb[base + 64]);
        float nxr = Ar * xr - Ai * xi + vr;
        float nxi = Ar * xi + Ai * xr + vi;
        xr = nxr; xi = nxi;
        Xb[base] = f2bf(xr); Xb[base + 64] = f2bf(xi);
        base += 128;
    }
}

// ---------------- GEMM1: Vb = bf16(U @ Mv^T), Ub = bf16(U) ----------------
// B (Mv, 128x512 bf16 = 128 KB) resident in LDS, staged ONCE (swizzled octets:
// stored p holds source octet p ^ (n&7) -> 8-way bank spread on ds_read_b128).
// A: fp32 global -> regs directly in MFMA fragment layout, cvt in-reg.
// 128-row block, 512 thr = 8 waves (4M x 2N), wave 32x64, MFMA 8/K-step.
// Main loop: NO barriers.
__global__ __launch_bounds__(512) void gemm1(const float* __restrict__ U,
                                             const unsigned short* __restrict__ Mv,
                                             unsigned short* __restrict__ Vb,
                                             unsigned short* __restrict__ Ub) {
    __shared__ __align__(16) unsigned short Bs[128 * 512];  // 128 KiB
    const int tid = threadIdx.x;
    const int lane = tid & 63;
    const int w = tid >> 6;             // 0..7
    const int wm = w >> 1, wn = w & 1;  // 4 x 2
    const int l15 = lane & 15, l4 = lane >> 4;
    const int row0 = blockIdx.x * 128;

    // stage whole Mv, swizzled source
#pragma unroll
    for (int i = 0; i < 16; ++i) {
        int c = i * 512 + tid;     // chunk 0..8191 over [128 rows][64 octets]
        int n = c >> 6;
        int p = c & 63;
        int ko = p ^ (n & 7);
        GLOAD_LDS16(Mv + (size_t)n * DMODEL + ko * 8, &Bs[(i * 512 + w * 64) * 8]);
    }
    asm volatile("s_waitcnt vmcnt(0)" ::: "memory");
    __builtin_amdgcn_s_barrier();
    __builtin_amdgcn_sched_barrier(0);

    f32x4 acc[2][4];
#pragma unroll
    for (int i = 0; i < 2; ++i)
#pragma unroll
        for (int j = 0; j < 4; ++j) acc[i][j] = (f32x4)(0.f);

#pragma unroll 2
    for (int k0 = 0; k0 < DMODEL; k0 += 32) {
        short8 af[2];
#pragma unroll
        for (int i = 0; i < 2; ++i) {
            int r = row0 + wm * 32 + i * 16 + l15;
            const float* ag = U + (size_t)r * DMODEL + k0 + l4 * 8;
            float4 a0 = ((const float4*)ag)[0];
            float4 a1 = ((const float4*)ag)[1];
            union { short8 s; uint4 u; } pk;
            pk.u.x = (unsigned)f2bf(a0.x) | ((unsigned)f2bf(a0.y) << 16);
            pk.u.y = (unsigned)f2bf(a0.z) | ((unsigned)f2bf(a0.w) << 16);
            pk.u.z = (unsigned)f2bf(a1.x) | ((unsigned)f2bf(a1.y) << 16);
            pk.u.w = (unsigned)f2bf(a1.z) | ((unsigned)f2bf(a1.w) << 16);
            af[i] = pk.s;
            if (wn == 0)
                *(uint4*)&Ub[(size_t)r * DMODEL + k0 + l4 * 8] = pk.u;
        }
        short8 bf[4];
#pragma unroll
        for (int j = 0; j < 4; ++j) {
            int n = wn * 64 + j * 16 + l15;
            int q = ((k0 >> 3) + l4) ^ (n & 7);
            bf[j] = *(const short8*)&Bs[n * DMODEL + q * 8];
        }
#pragma unroll
        for (int i = 0; i < 2; ++i)
#pragma unroll
            for (int j = 0; j < 4; ++j)
                acc[i][j] = __builtin_amdgcn_mfma_f32_16x16x32_bf16(af[i], bf[j], acc[i][j], 0, 0, 0);
    }

#pragma unroll
    for (int i = 0; i < 2; ++i) {
        int rbase = row0 + wm * 32 + i * 16 + l4 * 4;
#pragma unroll
        for (int j = 0; j < 4; ++j) {
            int col = wn * 64 + j * 16 + l15;
#pragma unroll
            for (int r = 0; r < 4; ++r)
                Vb[(size_t)(rbase + r) * 128 + col] = f2bf(acc[i][j][r]);
        }
    }
}

// ---------------- GEMM23: out = [Xb | Ub] @ W^T ----------------
// 256x256, BK=64, 2 phases/tile (K-halves), counted vmcnt(4), T2 swizzle.
// LDS: 2 slots x (A [2kh][256][32] 32KB + B 32KB) = 128 KiB.

#define STAGE_K(t, kh, j) do {                                                 \
    int c_ = (kh) * 1024 + (j) * 512 + tid;                                    \
    int ct_ = c_ ^ (((c_ >> 5) & 1) << 1);                                     \
    int r_ = (ct_ >> 2) & 255;                                                 \
    int kcol_ = (t) * 64 + (kh) * 32 + (ct_ & 3) * 8;                          \
    const unsigned short* asrc_ = (kcol_ < 128)                                \
        ? Xb + (size_t)(row0 + r_) * 128 + kcol_                               \
        : Ub + (size_t)(row0 + r_) * 512 + (kcol_ - 128);                      \
    GLOAD_LDS16(asrc_, &As[((t) & 1) * 16384 + ((kh) * 1024 + (j) * 512 + w * 64) * 8]); \
    GLOAD_LDS16(W + (size_t)(col0 + r_) * 640 + kcol_,                         \
                &Bs[((t) & 1) * 16384 + ((kh) * 1024 + (j) * 512 + w * 64) * 8]); \
} while (0)

#define LDAB(t, kh) do {                                                       \
    _Pragma("unroll") for (int i_ = 0; i_ < 8; ++i_) {                         \
        int r_ = wm * 128 + i_ * 16 + l15;                                     \
        int c_ = (l4 * 8) ^ (((r_ >> 3) & 1) << 4);                            \
        af[i_] = *(const short8*)&As[((t) & 1) * 16384 + (kh) * 8192 + r_ * 32 + c_]; \
    }                                                                          \
    _Pragma("unroll") for (int j_ = 0; j_ < 4; ++j_) {                         \
        int r_ = wn * 64 + j_ * 16 + l15;                                      \
        int c_ = (l4 * 8) ^ (((r_ >> 3) & 1) << 4);                            \
        bf[j_] = *(const short8*)&Bs[((t) & 1) * 16384 + (kh) * 8192 + r_ * 32 + c_]; \
    } } while (0)

#define MFMA32() do {                                                          \
    __builtin_amdgcn_s_setprio(1);                                             \
    _Pragma("unroll") for (int i_ = 0; i_ < 8; ++i_)                           \
    _Pragma("unroll") for (int j_ = 0; j_ < 4; ++j_)                           \
        acc[i_][j_] = __builtin_amdgcn_mfma_f32_16x16x32_bf16(                 \
            af[i_], bf[j_], acc[i_][j_], 0, 0, 0);                             \
    __builtin_amdgcn_s_setprio(0);                                             \
} while (0)

__global__ __launch_bounds__(512) void gemm23_8p(const unsigned short* __restrict__ Xb,
                                                 const unsigned short* __restrict__ Ub,
                                                 const unsigned short* __restrict__ W,
                                                 float* __restrict__ C) {
    __shared__ __align__(16) unsigned short As[2 * 16384];  // 64 KiB
    __shared__ __align__(16) unsigned short Bs[2 * 16384];  // 64 KiB
    const int tid = threadIdx.x;
    const int lane = tid & 63;
    const int w = tid >> 6;             // 0..7
    const int wm = w >> 2, wn = w & 3;  // 2 x 4
    const int l15 = lane & 15, l4 = lane >> 4;

    // T1: bijective XCD swizzle over 256 blocks
    int lin = blockIdx.y * gridDim.x + blockIdx.x;  // 0..255
    int sw = (lin & 7) * 32 + (lin >> 3);
    const int row0 = (sw & 127) * 256;
    const int col0 = (sw >> 7) * 256;

    f32x4 acc[8][4];
#pragma unroll
    for (int m = 0; m < 8; ++m)
#pragma unroll
        for (int n = 0; n < 4; ++n) acc[m][n] = (f32x4)(0.f);

    // prologue: stage tile 0 (kh0 then kh1) -> wait only kh0
    STAGE_K(0, 0, 0); STAGE_K(0, 0, 1);
    STAGE_K(0, 1, 0); STAGE_K(0, 1, 1);
    asm volatile("s_waitcnt vmcnt(4)" ::: "memory");
    __builtin_amdgcn_s_barrier();
    __builtin_amdgcn_sched_barrier(0);

    short8 af[8], bf[4];
    for (int t = 0; t < NT; ++t) {
        const bool pf = (t < NT - 1);
        // ---- phase A: K-half 0 ----
        LDAB(t, 0);
        if (pf) { STAGE_K(t + 1, 0, 0); STAGE_K(t + 1, 0, 1); }
        __builtin_amdgcn_s_barrier();
        __builtin_amdgcn_sched_barrier(0);
        MFMA32();
        if (pf) asm volatile("s_waitcnt vmcnt(4)" ::: "memory");   // t.kh1 done
        else    asm volatile("s_waitcnt vmcnt(0)" ::: "memory");
        __builtin_amdgcn_s_barrier();
        __builtin_amdgcn_sched_barrier(0);
        // ---- phase B: K-half 1 ----
        LDAB(t, 1);
        if (pf) { STAGE_K(t + 1, 1, 0); STAGE_K(t + 1, 1, 1); }
        __builtin_amdgcn_s_barrier();
        __builtin_amdgcn_sched_barrier(0);
        MFMA32();
        if (pf) asm volatile("s_waitcnt vmcnt(4)" ::: "memory");   // (t+1).kh0 done
        __builtin_amdgcn_s_barrier();
        __builtin_amdgcn_sched_barrier(0);
    }

#pragma unroll
    for (int m = 0; m < 8; ++m) {
        int rbase = row0 + wm * 128 + m * 16 + l4 * 4;
#pragma unroll
        for (int n = 0; n < 4; ++n) {
            int col = col0 + wn * 64 + n * 16 + l15;
#pragma unroll
            for (int r = 0; r < 4; ++r)
                C[(size_t)(rbase + r) * DMODEL + col] = acc[m][n][r];
        }
    }
}

// ---------------- launch ----------------

extern "C" void kernel_launch(void* const* d_in, const int* in_sizes, int n_in,
                              void* d_out, int out_size, void* d_ws, size_t ws_size,
                              hipStream_t stream) {
    const float* u      = (const float*)d_in[0];
    const float* logLr  = (const float*)d_in[1];
    const float* Li     = (const float*)d_in[2];
    const float* Br     = (const float*)d_in[3];
    const float* Bi     = (const float*)d_in[4];
    const float* Cr     = (const float*)d_in[5];
    const float* Ci     = (const float*)d_in[6];
    const float* D      = (const float*)d_in[7];
    const float* logDel = (const float*)d_in[8];
    float* out = (float*)d_out;

    const size_t M = (size_t)BATCH * SEQ;  // 32768
    unsigned short* Vb = (unsigned short*)d_ws;       // M*128
    unsigned short* Ub = Vb + M * 128;                // M*512
    unsigned short* Xb = Ub + M * 512;                // M*128
    unsigned short* Mv = Xb + M * 128;                // 128*512
    unsigned short* W  = Mv + 128 * 512;              // 512*640
    float* fp    = (float*)(W + 512 * 640);
    float* E     = fp;                     // 65536
    float* Carry = E + 65536;              // 65536
    float* ApR   = Carry + 65536;          // 4160
    float* ApI   = ApR + 4160;             // 4160
    float* sr    = ApI + 4160;             // 64
    float* si    = sr + 64;                // 64

    hipLaunchKernelGGL(k_consts, dim3(1), dim3(64), 0, stream,
                       logLr, Li, logDel, sr, si, ApR, ApI);
    hipLaunchKernelGGL(k_build_Mv, dim3(128), dim3(512), 0, stream, Br, Bi, sr, si, Mv);
    hipLaunchKernelGGL(k_build_W, dim3(512), dim3(640), 0, stream, Cr, Ci, D, W);

    // GEMM1: Vb = bf16(U @ Mv^T), Ub = bf16(U)
    hipLaunchKernelGGL(gemm1, dim3(M / 128), dim3(512), 0, stream, u, Mv, Vb, Ub);

    // scan: chunk-end states -> exact shuffle-scan carry -> seeded recurrence
    hipLaunchKernelGGL(k_scanA, dim3(256), dim3(128), 0, stream, Vb, ApR, ApI, E);
    hipLaunchKernelGGL(k_scanB, dim3(BATCH), dim3(512), 0, stream, E, Carry, ApR, ApI);
    hipLaunchKernelGGL(k_scanC, dim3(256), dim3(128), 0, stream, Vb, Carry, ApR, ApI, Xb);

    // GEMM23: out = [Xb | Ub] @ W^T
    hipLaunchKernelGGL(gemm23_8p, dim3(M / 256, DMODEL / 256), dim3(512), 0, stream,
                       Xb, Ub, W, out);
}

// Round 8
// 85.558 us; speedup vs baseline: 1.0813x; 1.0813x over previous
//
#include <hip/hip_runtime.h>
#include <hip/hip_bf16.h>
#include <stdint.h>

// S5 layer on MI355X — round 8:
//   gemm1  : REVERT to round-6 structure (64x128 tile, 8 waves, gload_lds B,
//            reg-staged A, ~4 blocks/CU) but emit Vb bf16 + Ub bf16.
//   scan   : exact 3-phase (shuffle-scan carry), V in bf16.
//   gemm23 : 256x256, BK=64, kh-phase ring (4 slots x 32KB), prefetch distance
//            3 phases (~HBM latency), ONE barrier + vmcnt(8) per phase, never
//            vmcnt(0) until drain. T2 swizzle + T5 setprio + T1 XCD swizzle.

#define BATCH 8
#define SEQ   4096
#define DMODEL 512
#define HALF  64
#define CHUNK 64
#define NCHUNK (SEQ / CHUNK)   // 64
#define NT    10               // 640/64 K-tiles in gemm23 (20 kh-phases)

typedef __attribute__((ext_vector_type(8))) short short8;
typedef __attribute__((ext_vector_type(4))) float f32x4;

__device__ __forceinline__ unsigned short f2bf(float f) {
    unsigned int u = __float_as_uint(f);
    u += 0x7fffu + ((u >> 16) & 1u);
    return (unsigned short)(u >> 16);
}
__device__ __forceinline__ float bf2f(unsigned short s) {
    return __uint_as_float((unsigned)s << 16);
}

#define GLOAD_LDS16(g, l)                                                    \
    __builtin_amdgcn_global_load_lds(                                        \
        (const __attribute__((address_space(1))) unsigned int*)(g),          \
        (__attribute__((address_space(3))) unsigned int*)(l), 16, 0, 0)

// ---------------- precompute ----------------

__global__ void k_consts(const float* __restrict__ logLr,
                         const float* __restrict__ Li_in,
                         const float* __restrict__ logDelta,
                         float* __restrict__ sr, float* __restrict__ si,
                         float* __restrict__ ApR, float* __restrict__ ApI) {
    int n = threadIdx.x;  // 0..63
    float Delta = expf(logDelta[0]);
    float llr = fminf(fmaxf(logLr[n], -10.f), 10.f);
    float Lr = -expf(llr);
    float Li = Li_in[n];
    float dr = 1.f - 0.5f * Delta * Lr;
    float di = -0.5f * Delta * Li;
    float dn = dr * dr + di * di;
    float nr = 1.f + 0.5f * Delta * Lr;
    float ni = 0.5f * Delta * Li;
    float Ar = (nr * dr + ni * di) / dn;
    float Ai = (ni * dr - nr * di) / dn;
    sr[n] = Delta * dr / dn;
    si[n] = -Delta * di / dn;
    float pr = 1.f, pi = 0.f;
    for (int k = 0; k <= CHUNK; ++k) {
        ApR[k * HALF + n] = pr;
        ApI[k * HALF + n] = pi;
        float npr = pr * Ar - pi * Ai;
        float npi = pr * Ai + pi * Ar;
        pr = npr; pi = npi;
    }
}

__global__ void k_build_Mv(const float* __restrict__ Br, const float* __restrict__ Bi,
                           const float* __restrict__ sr, const float* __restrict__ si,
                           unsigned short* __restrict__ Mv) {
    int np = blockIdx.x, p = threadIdx.x;
    int n = np & 63;
    float br = Br[n * DMODEL + p], bi = Bi[n * DMODEL + p];
    float v = (np < HALF) ? (sr[n] * br - si[n] * bi)
                          : (si[n] * br + sr[n] * bi);
    Mv[np * DMODEL + p] = f2bf(v);
}

__global__ void k_build_W(const float* __restrict__ Cr, const float* __restrict__ Ci,
                          const float* __restrict__ D, unsigned short* __restrict__ W) {
    int p = blockIdx.x, j = threadIdx.x;
    float v;
    if (j < HALF) v = 2.f * Cr[p * HALF + j];
    else if (j < 2 * HALF) v = -2.f * Ci[p * HALF + (j - HALF)];
    else v = D[p * DMODEL + (j - 2 * HALF)];
    W[p * 640 + j] = f2bf(v);
}

// ---------------- scan (exact; V in bf16) ----------------

__global__ void k_scanA(const unsigned short* __restrict__ Vb,
                        const float* __restrict__ ApR, const float* __restrict__ ApI,
                        float* __restrict__ E) {
    int tid = threadIdx.x;
    int n = tid & 63;
    int c = ((blockIdx.x & 31) << 1) + (tid >> 6);
    int b = blockIdx.x >> 5;
    float Ar = ApR[HALF + n], Ai = ApI[HALF + n];
    float xr = 0.f, xi = 0.f;
    size_t base = ((size_t)b * SEQ + (size_t)c * CHUNK) * 128 + n;
    for (int tl = 0; tl < CHUNK; ++tl) {
        float vr = bf2f(Vb[base]), vi = bf2f(Vb[base + 64]);
        float nxr = Ar * xr - Ai * xi + vr;
        float nxi = Ar * xi + Ai * xr + vi;
        xr = nxr; xi = nxi;
        base += 128;
    }
    int eidx = ((b * NCHUNK + c) * 2) * HALF + n;
    E[eidx] = xr; E[eidx + 64] = xi;
}

__global__ void k_scanB(const float* __restrict__ E, float* __restrict__ Carry,
                        const float* __restrict__ ApR, const float* __restrict__ ApI) {
    int lane = threadIdx.x & 63;   // chunk c
    int wv = threadIdx.x >> 6;     // 0..7
    int b = blockIdx.x;
    for (int n = wv; n < HALF; n += 8) {
        float wr = ApR[CHUNK * HALF + n], wi = ApI[CHUNK * HALF + n];  // A^64
        int idx = ((b * NCHUNK + lane) * 2) * HALF + n;
        float sR = E[idx], sI = E[idx + 64];
#pragma unroll
        for (int s = 1; s < 64; s <<= 1) {
            float pR = __shfl_up(sR, s, 64);
            float pI = __shfl_up(sI, s, 64);
            if (lane >= s) {
                sR += wr * pR - wi * pI;
                sI += wr * pI + wi * pR;
            }
            float nwr = wr * wr - wi * wi;
            float nwi = 2.f * wr * wi;
            wr = nwr; wi = nwi;
        }
        float cR = __shfl_up(sR, 1, 64);
        float cI = __shfl_up(sI, 1, 64);
        if (lane == 0) { cR = 0.f; cI = 0.f; }
        Carry[idx] = cR; Carry[idx + 64] = cI;
    }
}

__global__ void k_scanC(const unsigned short* __restrict__ Vb,
                        const float* __restrict__ Carry,
                        const float* __restrict__ ApR, const float* __restrict__ ApI,
                        unsigned short* __restrict__ Xb) {
    int tid = threadIdx.x;
    int n = tid & 63;
    int c = ((blockIdx.x & 31) << 1) + (tid >> 6);
    int b = blockIdx.x >> 5;
    int cidx = ((b * NCHUNK + c) * 2) * HALF + n;
    float xr = Carry[cidx], xi = Carry[cidx + 64];
    float Ar = ApR[HALF + n], Ai = ApI[HALF + n];
    size_t base = ((size_t)b * SEQ + (size_t)c * CHUNK) * 128 + n;
    for (int tl = 0; tl < CHUNK; ++tl) {
        float vr = bf2f(Vb[base]), vi = bf2f(Vb[base + 64]);
        float nxr = Ar * xr - Ai * xi + vr;
        float nxi = Ar * xi + Ai * xr + vi;
        xr = nxr; xi = nxi;
        Xb[base] = f2bf(xr); Xb[base + 64] = f2bf(xi);
        base += 128;
    }
}

// ---------------- GEMM1: Vb = bf16(U @ Mv^T), Ub = bf16(U) ----------------
// 64x128 tile, 512 thr = 8 waves (2M x 4N), wave 32x32 (acc[2][2]).
// grid M/64 = 512 -> ~4 blocks/CU (12.25KB LDS), high TLP for memory-bound.
__global__ __launch_bounds__(512) void gemm1(const float* __restrict__ U,
                                             const unsigned short* __restrict__ Mv,
                                             unsigned short* __restrict__ Vb,
                                             unsigned short* __restrict__ Ub) {
    __shared__ __align__(16) unsigned short As[64 * 32];
    __shared__ __align__(16) unsigned short Bs[128 * 32];
    const int tid = threadIdx.x;
    const int lane = tid & 63;
    const int w = tid >> 6;            // 0..7
    const int wm = w >> 2, wn = w & 3; // 2 x 4
    const int l15 = lane & 15, l4 = lane >> 4;
    const int row0 = blockIdx.x * 64;
    const int srow = tid >> 3;         // 0..63
    const int sh = (tid & 7) * 4;      // 0..28

    f32x4 acc[2][2];
#pragma unroll
    for (int m = 0; m < 2; ++m)
#pragma unroll
        for (int n = 0; n < 2; ++n) acc[m][n] = (f32x4)(0.f);

    for (int k0 = 0; k0 < DMODEL; k0 += 32) {
        const float4 av = *(const float4*)(U + (size_t)(row0 + srow) * DMODEL + k0 + sh);

        __syncthreads();   // prior tile's LDS reads complete

        // B tile 128x32 bf16 = 8KB via gload_lds
        GLOAD_LDS16(Mv + (size_t)(tid >> 2) * DMODEL + k0 + (tid & 3) * 8,
                    &Bs[(w * 64) * 8]);

        uint2 wa;
        wa.x = (unsigned)f2bf(av.x) | ((unsigned)f2bf(av.y) << 16);
        wa.y = (unsigned)f2bf(av.z) | ((unsigned)f2bf(av.w) << 16);
        *(uint2*)&As[srow * 32 + sh] = wa;
        *(uint2*)&Ub[(size_t)(row0 + srow) * DMODEL + k0 + sh] = wa;

        __syncthreads();   // vmcnt+lgkm drain: tiles staged

        short8 af[2], bf[2];
#pragma unroll
        for (int m = 0; m < 2; ++m)
            af[m] = *(const short8*)&As[(wm * 32 + m * 16 + l15) * 32 + l4 * 8];
#pragma unroll
        for (int n = 0; n < 2; ++n)
            bf[n] = *(const short8*)&Bs[(wn * 32 + n * 16 + l15) * 32 + l4 * 8];
#pragma unroll
        for (int m = 0; m < 2; ++m)
#pragma unroll
            for (int n = 0; n < 2; ++n)
                acc[m][n] = __builtin_amdgcn_mfma_f32_16x16x32_bf16(af[m], bf[n], acc[m][n], 0, 0, 0);
    }

#pragma unroll
    for (int m = 0; m < 2; ++m) {
        int rbase = row0 + wm * 32 + m * 16 + l4 * 4;
#pragma unroll
        for (int n = 0; n < 2; ++n) {
            int col = wn * 32 + n * 16 + l15;
#pragma unroll
            for (int r = 0; r < 4; ++r)
                Vb[(size_t)(rbase + r) * 128 + col] = f2bf(acc[m][n][r]);
        }
    }
}

// ---------------- GEMM23: out = [Xb | Ub] @ W^T ----------------
// 256x256, BK=64. kh-phase ring: 4 slots x (A 16KB + B 16KB); global kh index
// p = 2t+kh occupies slot p&3. Prefetch distance 3 phases; per phase:
// vmcnt(8) -> barrier -> ds_read kh_p -> stage kh_{p+3} -> MFMA32.

#define STAGE_K(t, kh, j) do {                                                 \
    int c_ = (kh) * 1024 + (j) * 512 + tid;                                    \
    int ct_ = c_ ^ (((c_ >> 5) & 1) << 1);                                     \
    int r_ = (ct_ >> 2) & 255;                                                 \
    int kcol_ = (t) * 64 + (kh) * 32 + (ct_ & 3) * 8;                          \
    const unsigned short* asrc_ = (kcol_ < 128)                                \
        ? Xb + (size_t)(row0 + r_) * 128 + kcol_                               \
        : Ub + (size_t)(row0 + r_) * 512 + (kcol_ - 128);                      \
    GLOAD_LDS16(asrc_, &As[((t) & 1) * 16384 + ((kh) * 1024 + (j) * 512 + w * 64) * 8]); \
    GLOAD_LDS16(W + (size_t)(col0 + r_) * 640 + kcol_,                         \
                &Bs[((t) & 1) * 16384 + ((kh) * 1024 + (j) * 512 + w * 64) * 8]); \
} while (0)

#define LDAB(t, kh) do {                                                       \
    _Pragma("unroll") for (int i_ = 0; i_ < 8; ++i_) {                         \
        int r_ = wm * 128 + i_ * 16 + l15;                                     \
        int c_ = (l4 * 8) ^ (((r_ >> 3) & 1) << 4);                            \
        af[i_] = *(const short8*)&As[((t) & 1) * 16384 + (kh) * 8192 + r_ * 32 + c_]; \
    }                                                                          \
    _Pragma("unroll") for (int j_ = 0; j_ < 4; ++j_) {                         \
        int r_ = wn * 64 + j_ * 16 + l15;                                      \
        int c_ = (l4 * 8) ^ (((r_ >> 3) & 1) << 4);                            \
        bf[j_] = *(const short8*)&Bs[((t) & 1) * 16384 + (kh) * 8192 + r_ * 32 + c_]; \
    } } while (0)

#define MFMA32() do {                                                          \
    __builtin_amdgcn_s_setprio(1);                                             \
    _Pragma("unroll") for (int i_ = 0; i_ < 8; ++i_)                           \
    _Pragma("unroll") for (int j_ = 0; j_ < 4; ++j_)                           \
        acc[i_][j_] = __builtin_amdgcn_mfma_f32_16x16x32_bf16(                 \
            af[i_], bf[j_], acc[i_][j_], 0, 0, 0);                             \
    __builtin_amdgcn_s_setprio(0);                                             \
} while (0)

#define PHASE_SYNC(N) do {                                                     \
    asm volatile("s_waitcnt vmcnt(" #N ")" ::: "memory");                      \
    __builtin_amdgcn_s_barrier();                                              \
    __builtin_amdgcn_sched_barrier(0);                                         \
} while (0)

__global__ __launch_bounds__(512) void gemm23_8p(const unsigned short* __restrict__ Xb,
                                                 const unsigned short* __restrict__ Ub,
                                                 const unsigned short* __restrict__ W,
                                                 float* __restrict__ C) {
    __shared__ __align__(16) unsigned short As[2 * 16384];  // 64 KiB = 4 kh-slots
    __shared__ __align__(16) unsigned short Bs[2 * 16384];  // 64 KiB
    const int tid = threadIdx.x;
    const int lane = tid & 63;
    const int w = tid >> 6;             // 0..7
    const int wm = w >> 2, wn = w & 3;  // 2 x 4
    const int l15 = lane & 15, l4 = lane >> 4;

    // T1: bijective XCD swizzle over 256 blocks
    int lin = blockIdx.y * gridDim.x + blockIdx.x;  // 0..255
    int sw = (lin & 7) * 32 + (lin >> 3);
    const int row0 = (sw & 127) * 256;
    const int col0 = (sw >> 7) * 256;

    f32x4 acc[8][4];
#pragma unroll
    for (int m = 0; m < 8; ++m)
#pragma unroll
        for (int n = 0; n < 4; ++n) acc[m][n] = (f32x4)(0.f);

    // prologue: stage kh-phases 0,1,2 (12 loads/thread in flight)
    STAGE_K(0, 0, 0); STAGE_K(0, 0, 1);
    STAGE_K(0, 1, 0); STAGE_K(0, 1, 1);
    STAGE_K(1, 0, 0); STAGE_K(1, 0, 1);

    short8 af[8], bf[4];
    for (int t = 0; t < NT - 1; ++t) {   // t = 0..8
        // phase A (p = 2t): consume kh0, stage kh_{2t+3} = (t+1, kh1)
        PHASE_SYNC(8);
        LDAB(t, 0);
        STAGE_K(t + 1, 1, 0); STAGE_K(t + 1, 1, 1);
        MFMA32();
        // phase B (p = 2t+1): consume kh1, stage kh_{2t+4} = (t+2, kh0)
        PHASE_SYNC(8);
        LDAB(t, 1);
        if (t < NT - 2) { STAGE_K(t + 2, 0, 0); STAGE_K(t + 2, 0, 1); }
        MFMA32();
    }
    // tail t = NT-1: phases 18 (vmcnt 4) and 19 (vmcnt 0)
    PHASE_SYNC(4);
    LDAB(NT - 1, 0);
    MFMA32();
    PHASE_SYNC(0);
    LDAB(NT - 1, 1);
    MFMA32();

#pragma unroll
    for (int m = 0; m < 8; ++m) {
        int rbase = row0 + wm * 128 + m * 16 + l4 * 4;
#pragma unroll
        for (int n = 0; n < 4; ++n) {
            int col = col0 + wn * 64 + n * 16 + l15;
#pragma unroll
            for (int r = 0; r < 4; ++r)
                C[(size_t)(rbase + r) * DMODEL + col] = acc[m][n][r];
        }
    }
}

// ---------------- launch ----------------

extern "C" void kernel_launch(void* const* d_in, const int* in_sizes, int n_in,
                              void* d_out, int out_size, void* d_ws, size_t ws_size,
                              hipStream_t stream) {
    const float* u      = (const float*)d_in[0];
    const float* logLr  = (const float*)d_in[1];
    const float* Li     = (const float*)d_in[2];
    const float* Br     = (const float*)d_in[3];
    const float* Bi     = (const float*)d_in[4];
    const float* Cr     = (const float*)d_in[5];
    const float* Ci     = (const float*)d_in[6];
    const float* D      = (const float*)d_in[7];
    const float* logDel = (const float*)d_in[8];
    float* out = (float*)d_out;

    const size_t M = (size_t)BATCH * SEQ;  // 32768
    unsigned short* Vb = (unsigned short*)d_ws;       // M*128
    unsigned short* Ub = Vb + M * 128;                // M*512
    unsigned short* Xb = Ub + M * 512;                // M*128
    unsigned short* Mv = Xb + M * 128;                // 128*512
    unsigned short* W  = Mv + 128 * 512;              // 512*640
    float* fp    = (float*)(W + 512 * 640);
    float* E     = fp;                     // 65536
    float* Carry = E + 65536;              // 65536
    float* ApR   = Carry + 65536;          // 4160
    float* ApI   = ApR + 4160;             // 4160
    float* sr    = ApI + 4160;             // 64
    float* si    = sr + 64;                // 64

    hipLaunchKernelGGL(k_consts, dim3(1), dim3(64), 0, stream,
                       logLr, Li, logDel, sr, si, ApR, ApI);
    hipLaunchKernelGGL(k_build_Mv, dim3(128), dim3(512), 0, stream, Br, Bi, sr, si, Mv);
    hipLaunchKernelGGL(k_build_W, dim3(512), dim3(640), 0, stream, Cr, Ci, D, W);

    // GEMM1: Vb = bf16(U @ Mv^T), Ub = bf16(U)
    hipLaunchKernelGGL(gemm1, dim3(M / 64), dim3(512), 0, stream, u, Mv, Vb, Ub);

    // scan: chunk-end states -> exact shuffle-scan carry -> seeded recurrence
    hipLaunchKernelGGL(k_scanA, dim3(256), dim3(128), 0, stream, Vb, ApR, ApI, E);
    hipLaunchKernelGGL(k_scanB, dim3(BATCH), dim3(512), 0, stream, E, Carry, ApR, ApI);
    hipLaunchKernelGGL(k_scanC, dim3(256), dim3(128), 0, stream, Vb, Carry, ApR, ApI, Xb);

    // GEMM23: out = [Xb | Ub] @ W^T
    hipLaunchKernelGGL(gemm23_8p, dim3(M / 256, DMODEL / 256), dim3(512), 0, stream,
                       Xb, Ub, W, out);
}